// Round 1
// baseline (6919.649 us; speedup 1.0000x reference)
//
#include <hip/hip_runtime.h>

#define SS 2048
#define BATCH 512
#define NB 2

// ---------- fast activations (fp32, ~1-2 ulp) ----------
__device__ __forceinline__ float fast_rcp(float a) { return __builtin_amdgcn_rcpf(a); }

__device__ __forceinline__ float sigm(float v) {
  // 1/(1+e^-v); e^-v -> inf for very negative v gives rcp(inf)=0, correct limit.
  return fast_rcp(1.0f + __expf(-v));
}

__device__ __forceinline__ float tanh_fast(float v) {
  // clamp to avoid e^{2x} overflow -> NaN; tanh saturates to +-1 well before 15
  float t = fminf(15.0f, fmaxf(-15.0f, v));
  float e = __expf(2.0f * t);
  return (e - 1.0f) * fast_rcp(e + 1.0f);
}

// ---------- partial matvec: acc[g] += sum_{kk<16} w[g][kk] * hsrc[k0+kk] ----------
__device__ __forceinline__ void matvec_part(const float (&w)[4][16],
                                            const float* hsrc, int k0,
                                            float (&acc)[4]) {
  float hv[16];
#pragma unroll
  for (int c4 = 0; c4 < 4; ++c4) {
    const float4 h4 = *(const float4*)(hsrc + k0 + 4 * c4);
    hv[4 * c4 + 0] = h4.x; hv[4 * c4 + 1] = h4.y;
    hv[4 * c4 + 2] = h4.z; hv[4 * c4 + 3] = h4.w;
  }
#pragma unroll
  for (int g = 0; g < 4; ++g) {
    float a = acc[g];
#pragma unroll
    for (int kk = 0; kk < 16; ++kk) a = fmaf(w[g][kk], hv[kk], a);
    acc[g] = a;
  }
}

// ---------- split-K reduce (over kq via shfl_xor 16,32) + gate activations + c/h update ----------
__device__ __forceinline__ float lstm_finish(float (&acc)[4],
                                             const float (&extra)[4],
                                             float& cst) {
#pragma unroll
  for (int g = 0; g < 4; ++g) {
    float a = acc[g];
    a += __shfl_xor(a, 16, 64);
    a += __shfl_xor(a, 32, 64);
    acc[g] = a + extra[g];
  }
  const float gi = sigm(acc[0]);       // i
  const float gf = sigm(acc[1]);       // f
  const float gg = tanh_fast(acc[2]);  // g
  const float go = sigm(acc[3]);       // o
  const float cn = fmaf(gf, cst, gi * gg);
  cst = cn;
  return go * tanh_fast(cn);
}

// One timestep: 3 layers, ping-pong h buffers by parity; 2 barriers.
// Barrier after layer-2 is provably unnecessary with ping-pong buffers:
// every write-read pair across iterations is separated by >=1 of the 2 barriers.
template <int CUR, int NXT>
__device__ __forceinline__ void lstm_step(
    float (&hb)[2][3][NB][64],
    const float (&whh0)[4][16], const float (&wih1)[4][16],
    const float (&whh1)[4][16], const float (&wih2)[4][16],
    const float (&whh2)[4][16], const float (&wi0)[4][4],
    const float (&bs0)[4], const float (&bs1)[4], const float (&bs2)[4],
    float (&c0)[NB], float (&c1)[NB], float (&c2)[NB],
    const float (&xin)[NB][4], int j, int kq, int k0) {
  // ---- layer 0 ----
#pragma unroll
  for (int b = 0; b < NB; ++b) {
    float acc[4] = {0.f, 0.f, 0.f, 0.f};
    matvec_part(whh0, &hb[CUR][0][b][0], k0, acc);
    float extra[4];
#pragma unroll
    for (int g = 0; g < 4; ++g) {
      float xp = bs0[g];
#pragma unroll
      for (int f2 = 0; f2 < 4; ++f2) xp = fmaf(wi0[g][f2], xin[b][f2], xp);
      extra[g] = xp;
    }
    const float hn = lstm_finish(acc, extra, c0[b]);
    if (kq == 0) hb[NXT][0][b][j] = hn;
  }
  __syncthreads();
  // ---- layer 1 ----
#pragma unroll
  for (int b = 0; b < NB; ++b) {
    float acc[4] = {0.f, 0.f, 0.f, 0.f};
    matvec_part(wih1, &hb[NXT][0][b][0], k0, acc);  // input = h0 (new)
    matvec_part(whh1, &hb[CUR][1][b][0], k0, acc);  // recurrent = h1 (old)
    const float hn = lstm_finish(acc, bs1, c1[b]);
    if (kq == 0) hb[NXT][1][b][j] = hn;
  }
  __syncthreads();
  // ---- layer 2 ----
#pragma unroll
  for (int b = 0; b < NB; ++b) {
    float acc[4] = {0.f, 0.f, 0.f, 0.f};
    matvec_part(wih2, &hb[NXT][1][b][0], k0, acc);  // input = h1 (new)
    matvec_part(whh2, &hb[CUR][2][b][0], k0, acc);  // recurrent = h2 (old)
    const float hn = lstm_finish(acc, bs2, c2[b]);
    if (kq == 0) hb[NXT][2][b][j] = hn;
  }
  // no trailing barrier (ping-pong; next step's first conflicting access is
  // separated by the two barriers above of the following invocation)
}

__global__ void __launch_bounds__(256, 1)
lstm3_kernel(const float* __restrict__ x,
             const float* __restrict__ Wih0, const float* __restrict__ Whh0,
             const float* __restrict__ bih0, const float* __restrict__ bhh0,
             const float* __restrict__ Wih1, const float* __restrict__ Whh1,
             const float* __restrict__ bih1, const float* __restrict__ bhh1,
             const float* __restrict__ Wih2, const float* __restrict__ Whh2,
             const float* __restrict__ bih2, const float* __restrict__ bhh2,
             const float* __restrict__ fcw, const float* __restrict__ fcb,
             float* __restrict__ out) {
  __shared__ float hb[2][3][NB][64];  // [parity][layer][b][k], 3 KB
  const int tid = threadIdx.x;
  const int wave = tid >> 6;
  const int lane = tid & 63;
  const int j = (wave << 4) | (lane & 15);  // hidden unit 0..63
  const int kq = lane >> 4;                 // K-quarter 0..3 (shfl pairs in-wave)
  const int k0 = kq << 4;
  const int bbase = blockIdx.x * NB;

  // register-resident weight fragments: 4 gate-rows x 16-wide K-quarter each
  float whh0[4][16], wih1[4][16], whh1[4][16], wih2[4][16], whh2[4][16];
  float wi0[4][4], bs0[4], bs1[4], bs2[4];
#pragma unroll
  for (int g = 0; g < 4; ++g) {
    const int r = (g << 6) + j;   // PyTorch gate order rows: i,f,g,o
    const int ro = r * 64 + k0;
#pragma unroll
    for (int c4 = 0; c4 < 4; ++c4) {
      const float4 a0 = *(const float4*)&Whh0[ro + 4 * c4];
      const float4 a1 = *(const float4*)&Wih1[ro + 4 * c4];
      const float4 a2 = *(const float4*)&Whh1[ro + 4 * c4];
      const float4 a3 = *(const float4*)&Wih2[ro + 4 * c4];
      const float4 a4 = *(const float4*)&Whh2[ro + 4 * c4];
      whh0[g][4*c4+0]=a0.x; whh0[g][4*c4+1]=a0.y; whh0[g][4*c4+2]=a0.z; whh0[g][4*c4+3]=a0.w;
      wih1[g][4*c4+0]=a1.x; wih1[g][4*c4+1]=a1.y; wih1[g][4*c4+2]=a1.z; wih1[g][4*c4+3]=a1.w;
      whh1[g][4*c4+0]=a2.x; whh1[g][4*c4+1]=a2.y; whh1[g][4*c4+2]=a2.z; whh1[g][4*c4+3]=a2.w;
      wih2[g][4*c4+0]=a3.x; wih2[g][4*c4+1]=a3.y; wih2[g][4*c4+2]=a3.z; wih2[g][4*c4+3]=a3.w;
      whh2[g][4*c4+0]=a4.x; whh2[g][4*c4+1]=a4.y; whh2[g][4*c4+2]=a4.z; whh2[g][4*c4+3]=a4.w;
    }
    const float4 w0 = *(const float4*)&Wih0[r * 4];
    wi0[g][0]=w0.x; wi0[g][1]=w0.y; wi0[g][2]=w0.z; wi0[g][3]=w0.w;
    bs0[g] = bih0[r] + bhh0[r];
    bs1[g] = bih1[r] + bhh1[r];
    bs2[g] = bih2[r] + bhh2[r];
  }

  float c0[NB], c1[NB], c2[NB];
#pragma unroll
  for (int b = 0; b < NB; ++b) { c0[b] = 0.f; c1[b] = 0.f; c2[b] = 0.f; }

  {  // zero both parities of h
    float* p = &hb[0][0][0][0];
    for (int i = tid; i < 2 * 3 * NB * 64; i += 256) p[i] = 0.f;
  }

  // x(t) register prefetch buffers (broadcast loads; same addr across lanes)
  float xc[NB][4], xn[NB][4];
#pragma unroll
  for (int b = 0; b < NB; ++b) {
    const float4 v = *(const float4*)&x[(size_t)(bbase + b) * SS * 4];
    xc[b][0]=v.x; xc[b][1]=v.y; xc[b][2]=v.z; xc[b][3]=v.w;
  }
  __syncthreads();

  for (int t = 0; t < SS; t += 2) {
    // prefetch x(t+1) (consumed one step later)
#pragma unroll
    for (int b = 0; b < NB; ++b) {
      const float4 v = *(const float4*)&x[((size_t)(bbase + b) * SS + (t + 1)) * 4];
      xn[b][0]=v.x; xn[b][1]=v.y; xn[b][2]=v.z; xn[b][3]=v.w;
    }
    lstm_step<0, 1>(hb, whh0, wih1, whh1, wih2, whh2, wi0, bs0, bs1, bs2,
                    c0, c1, c2, xc, j, kq, k0);
    const int tp = (t + 2 < SS) ? (t + 2) : (SS - 1);
#pragma unroll
    for (int b = 0; b < NB; ++b) {
      const float4 v = *(const float4*)&x[((size_t)(bbase + b) * SS + tp) * 4];
      xc[b][0]=v.x; xc[b][1]=v.y; xc[b][2]=v.z; xc[b][3]=v.w;
    }
    lstm_step<1, 0>(hb, whh0, wih1, whh1, wih2, whh2, wi0, bs0, bs1, bs2,
                    c0, c1, c2, xn, j, kq, k0);
  }
  __syncthreads();  // publish final h2 (lives in parity 0 after t=2047)

  // fc: out[b][o] = fc_b[o] + sum_j fc_w[o][j] * h2_last[b][j]
  if (tid < NB * 2) {
    const int b = tid >> 1, o = tid & 1;
    float s = fcb[o];
#pragma unroll
    for (int jj = 0; jj < 64; ++jj)
      s = fmaf(fcw[o * 64 + jj], hb[0][2][b][jj], s);
    out[(bbase + b) * 2 + o] = s;
  }
}

extern "C" void kernel_launch(void* const* d_in, const int* in_sizes, int n_in,
                              void* d_out, int out_size, void* d_ws, size_t ws_size,
                              hipStream_t stream) {
  const float* x    = (const float*)d_in[0];
  const float* Wih0 = (const float*)d_in[1];
  const float* Whh0 = (const float*)d_in[2];
  const float* bih0 = (const float*)d_in[3];
  const float* bhh0 = (const float*)d_in[4];
  const float* Wih1 = (const float*)d_in[5];
  const float* Whh1 = (const float*)d_in[6];
  const float* bih1 = (const float*)d_in[7];
  const float* bhh1 = (const float*)d_in[8];
  const float* Wih2 = (const float*)d_in[9];
  const float* Whh2 = (const float*)d_in[10];
  const float* bih2 = (const float*)d_in[11];
  const float* bhh2 = (const float*)d_in[12];
  const float* fcw  = (const float*)d_in[13];
  const float* fcb  = (const float*)d_in[14];
  float* out = (float*)d_out;

  lstm3_kernel<<<dim3(BATCH / NB), dim3(256), 0, stream>>>(
      x, Wih0, Whh0, bih0, bhh0, Wih1, Whh1, bih1, bhh1,
      Wih2, Whh2, bih2, bhh2, fcw, fcb, out);
}

// Round 2
// 4618.452 us; speedup vs baseline: 1.4983x; 1.4983x over previous
//
#include <hip/hip_runtime.h>

#define SS 2048
#define BATCH 512
#define NB 2          // batch elements per block
#define NT 512        // threads per block: 64 j * 8 ko

// ---------- fast fp32 activations ----------
__device__ __forceinline__ float fast_rcp(float a) { return __builtin_amdgcn_rcpf(a); }

__device__ __forceinline__ float sigm(float v) {
  // 1/(1+2^(-log2e * v)); rcp(inf)=0 handles v->-inf correctly.
  return fast_rcp(1.0f + __builtin_amdgcn_exp2f(-1.4426950408889634f * v));
}

__device__ __forceinline__ float tanh_fast(float v) {
  // tanh(v) = 1 - 2/(1+2^(2*log2e*v)); NaN-free at both infinities.
  const float r = fast_rcp(1.0f + __builtin_amdgcn_exp2f(2.8853900817779268f * v));
  return fmaf(-2.0f, r, 1.0f);
}

// ---------- DPP butterfly add over the 8 ko lanes (lane bits 0..2) ----------
template <int CTRL>
__device__ __forceinline__ float dpp_add(float v) {
  const int sh = __builtin_amdgcn_update_dpp(0, __float_as_int(v), CTRL, 0xf, 0xf, true);
  return v + __int_as_float(sh);
}
__device__ __forceinline__ float reduce8(float v) {
  v = dpp_add<0xB1>(v);   // quad_perm(1,0,3,2)  = xor1
  v = dpp_add<0x4E>(v);   // quad_perm(2,3,0,1)  = xor2
  v = dpp_add<0x141>(v);  // row_half_mirror     = xor7 -> completes 8-lane sum
  return v;
}

// ---------- partial matvec over this thread's 8-wide K slice ----------
__device__ __forceinline__ void mv8(const float (&w)[4][8], const float* hsrc,
                                    float (&acc)[4]) {
  const float4 a = *(const float4*)(hsrc);
  const float4 b = *(const float4*)(hsrc + 4);
  const float hv[8] = {a.x, a.y, a.z, a.w, b.x, b.y, b.z, b.w};
#pragma unroll
  for (int g = 0; g < 4; ++g) {
    float s = acc[g];
#pragma unroll
    for (int kk = 0; kk < 8; ++kk) s = fmaf(w[g][kk], hv[kk], s);
    acc[g] = s;
  }
}

// reduce + gate activations + c/h update. acc[] holds this lane's K-partials;
// biases (pre-scaled by 1/8) were folded into acc init.
__device__ __forceinline__ float lstm_finish(float (&acc)[4], float& cst) {
#pragma unroll
  for (int g = 0; g < 4; ++g) acc[g] = reduce8(acc[g]);
  const float gi = sigm(acc[0]);
  const float gf = sigm(acc[1]);
  const float gg = tanh_fast(acc[2]);
  const float go = sigm(acc[3]);
  const float cn = fmaf(gf, cst, gi * gg);
  cst = cn;
  return go * tanh_fast(cn);
}

__device__ __forceinline__ float sel4(float4 v, int m) {
  float r = v.x;
  r = (m == 1) ? v.y : r;
  r = (m == 2) ? v.z : r;
  r = (m == 3) ? v.w : r;
  return r;
}

// One timestep. Ping-pong parity CUR -> NXT; 2 barriers.
// Whh0/Whh1 old-h matvecs hoisted above barrier A (safe under ping-pong);
// Whh2 old-h matvec must stay after barrier B (hazard vs next step otherwise).
template <int CUR, int NXT>
__device__ __forceinline__ void lstm_step(
    float (&hb)[2][3][NB][64],
    const float (&whh0)[4][8], const float (&wih1)[4][8],
    const float (&whh1)[4][8], const float (&wih2)[4][8],
    const float (&whh2)[4][8],
    const float (&wi0f)[4],               // Wih0 col (ko&3), pre-scaled 0.5
    const float (&bs0)[4], const float (&bs1)[4], const float (&bs2)[4],
    float (&c0)[NB], float (&c1)[NB], float (&c2)[NB],
    const float (&xs)[NB],                // pre-selected x component for lane
    int j, int ko, int k0) {
  float acc0[NB][4], acc1[NB][4];
  // ---- S1: both old-h matvecs that are barrier-safe ----
#pragma unroll
  for (int b = 0; b < NB; ++b) {
#pragma unroll
    for (int g = 0; g < 4; ++g) {
      acc0[b][g] = fmaf(wi0f[g], xs[b], bs0[g]);  // bias(1/8) + 0.5*x-proj col
      acc1[b][g] = bs1[g];
    }
    mv8(whh0, &hb[CUR][0][b][k0], acc0[b]);
    mv8(whh1, &hb[CUR][1][b][k0], acc1[b]);
  }
  // ---- finish layer 0 ----
#pragma unroll
  for (int b = 0; b < NB; ++b) {
    const float hn = lstm_finish(acc0[b], c0[b]);
    if (ko == 0) hb[NXT][0][b][j] = hn;
  }
  __syncthreads();  // barrier A
  // ---- layer 1: add fresh-h0 matvec ----
#pragma unroll
  for (int b = 0; b < NB; ++b) {
    mv8(wih1, &hb[NXT][0][b][k0], acc1[b]);
    const float hn = lstm_finish(acc1[b], c1[b]);
    if (ko == 0) hb[NXT][1][b][j] = hn;
  }
  __syncthreads();  // barrier B
  // ---- layer 2 ----
#pragma unroll
  for (int b = 0; b < NB; ++b) {
    float acc2[4];
#pragma unroll
    for (int g = 0; g < 4; ++g) acc2[g] = bs2[g];
    mv8(wih2, &hb[NXT][1][b][k0], acc2);
    mv8(whh2, &hb[CUR][2][b][k0], acc2);
    const float hn = lstm_finish(acc2, c2[b]);
    if (ko == 0) hb[NXT][2][b][j] = hn;
  }
  // no trailing barrier (ping-pong)
}

__global__ void __launch_bounds__(NT, 2)
lstm3_kernel(const float* __restrict__ x,
             const float* __restrict__ Wih0, const float* __restrict__ Whh0,
             const float* __restrict__ bih0, const float* __restrict__ bhh0,
             const float* __restrict__ Wih1, const float* __restrict__ Whh1,
             const float* __restrict__ bih1, const float* __restrict__ bhh1,
             const float* __restrict__ Wih2, const float* __restrict__ Whh2,
             const float* __restrict__ bih2, const float* __restrict__ bhh2,
             const float* __restrict__ fcw, const float* __restrict__ fcb,
             float* __restrict__ out) {
  __shared__ float hb[2][3][NB][64];  // [parity][layer][b][k], 3 KB
  const int tid = threadIdx.x;
  const int j = tid >> 3;       // hidden unit 0..63
  const int ko = tid & 7;       // K-octant (lane bits 0..2 -> DPP reduce in-wave)
  const int k0 = ko << 3;
  const int bbase = blockIdx.x * NB;

  // register-resident weights: 4 gate-rows x 8-wide K slice per matrix
  float whh0[4][8], wih1[4][8], whh1[4][8], wih2[4][8], whh2[4][8];
  float wi0f[4], bs0[4], bs1[4], bs2[4];
#pragma unroll
  for (int g = 0; g < 4; ++g) {
    const int r = (g << 6) + j;   // PyTorch gate-order rows: i,f,g,o
    const int ro = (r << 6) + k0;
    *(float4*)&whh0[g][0] = *(const float4*)&Whh0[ro];
    *(float4*)&whh0[g][4] = *(const float4*)&Whh0[ro + 4];
    *(float4*)&wih1[g][0] = *(const float4*)&Wih1[ro];
    *(float4*)&wih1[g][4] = *(const float4*)&Wih1[ro + 4];
    *(float4*)&whh1[g][0] = *(const float4*)&Whh1[ro];
    *(float4*)&whh1[g][4] = *(const float4*)&Whh1[ro + 4];
    *(float4*)&wih2[g][0] = *(const float4*)&Wih2[ro];
    *(float4*)&wih2[g][4] = *(const float4*)&Wih2[ro + 4];
    *(float4*)&whh2[g][0] = *(const float4*)&Whh2[ro];
    *(float4*)&whh2[g][4] = *(const float4*)&Whh2[ro + 4];
    wi0f[g] = 0.5f * Wih0[r * 4 + (ko & 3)];        // col split over ko lanes
    bs0[g] = 0.125f * (bih0[r] + bhh0[r]);          // pre-scaled: reduce8 x8
    bs1[g] = 0.125f * (bih1[r] + bhh1[r]);
    bs2[g] = 0.125f * (bih2[r] + bhh2[r]);
  }

  float c0[NB], c1[NB], c2[NB];
#pragma unroll
  for (int b = 0; b < NB; ++b) { c0[b] = 0.f; c1[b] = 0.f; c2[b] = 0.f; }

  {  // zero both parities of h
    float* p = &hb[0][0][0][0];
    for (int i = tid; i < 2 * 3 * NB * 64; i += NT) p[i] = 0.f;
  }

  // x prefetch: one pre-selected component per buffer per batch elem
  const int m = ko & 3;
  float xcs[NB], xns[NB];
#pragma unroll
  for (int b = 0; b < NB; ++b)
    xcs[b] = sel4(*(const float4*)&x[(size_t)(bbase + b) * SS * 4], m);
  __syncthreads();

#pragma unroll 1
  for (int t = 0; t < SS; t += 2) {
#pragma unroll
    for (int b = 0; b < NB; ++b)
      xns[b] = sel4(*(const float4*)&x[((size_t)(bbase + b) * SS + (t + 1)) * 4], m);
    lstm_step<0, 1>(hb, whh0, wih1, whh1, wih2, whh2, wi0f, bs0, bs1, bs2,
                    c0, c1, c2, xcs, j, ko, k0);
    const int tp = (t + 2 < SS) ? (t + 2) : (SS - 1);
#pragma unroll
    for (int b = 0; b < NB; ++b)
      xcs[b] = sel4(*(const float4*)&x[((size_t)(bbase + b) * SS + tp) * 4], m);
    lstm_step<1, 0>(hb, whh0, wih1, whh1, wih2, whh2, wi0f, bs0, bs1, bs2,
                    c0, c1, c2, xns, j, ko, k0);
  }
  __syncthreads();  // publish final h2 (parity 0 after t=2047)

  // fc: out[b][o] = fc_b[o] + sum_j fc_w[o][j] * h2_last[b][j]
  if (tid < NB * 2) {
    const int b = tid >> 1, o = tid & 1;
    float s = fcb[o];
#pragma unroll
    for (int jj = 0; jj < 64; ++jj)
      s = fmaf(fcw[o * 64 + jj], hb[0][2][b][jj], s);
    out[(bbase + b) * 2 + o] = s;
  }
}

extern "C" void kernel_launch(void* const* d_in, const int* in_sizes, int n_in,
                              void* d_out, int out_size, void* d_ws, size_t ws_size,
                              hipStream_t stream) {
  const float* x    = (const float*)d_in[0];
  const float* Wih0 = (const float*)d_in[1];
  const float* Whh0 = (const float*)d_in[2];
  const float* bih0 = (const float*)d_in[3];
  const float* bhh0 = (const float*)d_in[4];
  const float* Wih1 = (const float*)d_in[5];
  const float* Whh1 = (const float*)d_in[6];
  const float* bih1 = (const float*)d_in[7];
  const float* bhh1 = (const float*)d_in[8];
  const float* Wih2 = (const float*)d_in[9];
  const float* Whh2 = (const float*)d_in[10];
  const float* bih2 = (const float*)d_in[11];
  const float* bhh2 = (const float*)d_in[12];
  const float* fcw  = (const float*)d_in[13];
  const float* fcb  = (const float*)d_in[14];
  float* out = (float*)d_out;

  lstm3_kernel<<<dim3(BATCH / NB), dim3(NT), 0, stream>>>(
      x, Wih0, Whh0, bih0, bhh0, Wih1, Whh1, bih1, bhh1,
      Wih2, Whh2, bih2, bhh2, fcw, fcb, out);
}

// Round 3
// 4275.281 us; speedup vs baseline: 1.6185x; 1.0803x over previous
//
#include <hip/hip_runtime.h>

#define SS 2048
#define BATCH 512
#define NB 2          // batch elements per block
#define NT 512        // threads per block: 64 j * 8 ko

// ---------- fast fp32 helpers ----------
__device__ __forceinline__ float fast_rcp(float a) { return __builtin_amdgcn_rcpf(a); }
__device__ __forceinline__ float fast_exp2(float a) { return __builtin_amdgcn_exp2f(a); }

// ---------- DPP add (quad-level xor1 / xor2) ----------
template <int CTRL>
__device__ __forceinline__ float dpp_add(float v) {
  const int sh = __builtin_amdgcn_update_dpp(0, __float_as_int(v), CTRL, 0xf, 0xf, true);
  return v + __int_as_float(sh);
}

// ---------- ds_swizzle (BitMode: offset = xor<<10 | or<<5 | and) ----------
template <int OFF>
__device__ __forceinline__ float swzf(float v) {
  return __int_as_float(__builtin_amdgcn_ds_swizzle(__float_as_int(v), OFF));
}

// ---------- partial matvec over this thread's 8-wide K slice ----------
__device__ __forceinline__ void mv8(const float (&w)[4][8], const float* hsrc,
                                    float (&acc)[4]) {
  const float4 a = *(const float4*)(hsrc);
  const float4 b = *(const float4*)(hsrc + 4);
  const float hv[8] = {a.x, a.y, a.z, a.w, b.x, b.y, b.z, b.w};
#pragma unroll
  for (int g = 0; g < 4; ++g) {
    float s = acc[g];
#pragma unroll
    for (int kk = 0; kk < 8; ++kk) s = fmaf(w[g][kk], hv[kk], s);
    acc[g] = s;
  }
}

// 2-stage DPP reduce (4 gates), select gate ko&3, finish reduce with xor4.
// Returns this lane's gate pre-activation (sum over all 64 K).
__device__ __forceinline__ float redsel(float (&a)[4], bool kb0, bool kb1) {
#pragma unroll
  for (int g = 0; g < 4; ++g) {
    a[g] = dpp_add<0xB1>(a[g]);   // quad_perm(1,0,3,2) = xor1
    a[g] = dpp_add<0x4E>(a[g]);   // quad_perm(2,3,0,1) = xor2
  }
  const float s01 = kb0 ? a[1] : a[0];
  const float s23 = kb0 ? a[3] : a[2];
  float s = kb1 ? s23 : s01;          // gate (ko&3), half (ko>>2)
  s += swzf<0x101F>(s);               // xor4 -> full K sum
  return s;
}

// Branchless activation (per-lane consts) + gate broadcast + c/h update.
// act = aact * rcp(1 + exp2(kact * pre)) + bact  (sigmoid or tanh per lane)
__device__ __forceinline__ float gate_finish(float pre, float kact, float aact,
                                             float bact, float& c) {
  const float e = fast_exp2(kact * pre);
  const float r = fast_rcp(1.0f + e);
  const float a = fmaf(aact, r, bact);
  // broadcast the 4 gate values to all 8 lanes of the j-group
  const float vi = swzf<0x018>(a);    // lane (base&0x18)|0 : gate i
  const float vf = swzf<0x038>(a);    // gate f
  const float vg = swzf<0x058>(a);    // gate g
  const float vo = swzf<0x078>(a);    // gate o
  c = fmaf(vf, c, vi * vg);
  const float te = fast_exp2(2.8853900817779268f * c);   // tanh(c)
  const float tr = fast_rcp(1.0f + te);
  const float t = vo * tr;
  return fmaf(-2.0f, t, vo);          // o * tanh(c)
}

// One timestep. Ping-pong parity CUR -> NXT; 2 barriers (hazard analysis
// unchanged from round 2: every conflicting write/read pair is separated by
// >= 2 of the per-step barriers).
template <int CUR, int NXT>
__device__ __forceinline__ void lstm_step(
    float (&hb)[2][3][NB][64],
    const float (&whh0)[4][8], const float (&wih1)[4][8],
    const float (&whh1)[4][8], const float (&wih2)[4][8],
    const float (&whh2)[4][8],
    const float (&wi0l)[4],   // per-lane Wih0 row (gate ko&3)
    float b0l, float b1l, float b2l,          // per-lane biases
    float kact, float aact, float bact,       // per-lane activation consts
    float (&c0)[NB], float (&c1)[NB], float (&c2)[NB],
    const float (&xin)[NB][4], int j, int ko, int k0,
    bool kb0, bool kb1, bool wr) {
  float p0[NB][4], p1[NB][4];
  // ---- S1: barrier-safe old-h matvecs ----
#pragma unroll
  for (int b = 0; b < NB; ++b) {
#pragma unroll
    for (int g = 0; g < 4; ++g) { p0[b][g] = 0.f; p1[b][g] = 0.f; }
    mv8(whh0, &hb[CUR][0][b][k0], p0[b]);
    mv8(whh1, &hb[CUR][1][b][k0], p1[b]);
  }
  // ---- finish layer 0 (adds per-lane x-projection + bias) ----
#pragma unroll
  for (int b = 0; b < NB; ++b) {
    float s = redsel(p0[b], kb0, kb1);
    float d = b0l;
#pragma unroll
    for (int f2 = 0; f2 < 4; ++f2) d = fmaf(wi0l[f2], xin[b][f2], d);
    const float hn = gate_finish(s + d, kact, aact, bact, c0[b]);
    if (wr) hb[NXT][0][b][j] = hn;
  }
  __syncthreads();  // barrier A
  // ---- layer 1 ----
#pragma unroll
  for (int b = 0; b < NB; ++b) {
    mv8(wih1, &hb[NXT][0][b][k0], p1[b]);
    const float hn = gate_finish(redsel(p1[b], kb0, kb1) + b1l, kact, aact, bact, c1[b]);
    if (wr) hb[NXT][1][b][j] = hn;
  }
  __syncthreads();  // barrier B
  // ---- layer 2 ----
#pragma unroll
  for (int b = 0; b < NB; ++b) {
    float p2[4] = {0.f, 0.f, 0.f, 0.f};
    mv8(wih2, &hb[NXT][1][b][k0], p2);
    mv8(whh2, &hb[CUR][2][b][k0], p2);
    const float hn = gate_finish(redsel(p2, kb0, kb1) + b2l, kact, aact, bact, c2[b]);
    if (wr) hb[NXT][2][b][j] = hn;
  }
}

__global__ void __launch_bounds__(NT, 2)
lstm3_kernel(const float* __restrict__ x,
             const float* __restrict__ Wih0, const float* __restrict__ Whh0,
             const float* __restrict__ bih0, const float* __restrict__ bhh0,
             const float* __restrict__ Wih1, const float* __restrict__ Whh1,
             const float* __restrict__ bih1, const float* __restrict__ bhh1,
             const float* __restrict__ Wih2, const float* __restrict__ Whh2,
             const float* __restrict__ bih2, const float* __restrict__ bhh2,
             const float* __restrict__ fcw, const float* __restrict__ fcb,
             float* __restrict__ out) {
  __shared__ float hb[2][3][NB][64];  // [parity][layer][b][k], 3 KB
  const int tid = threadIdx.x;
  const int j = tid >> 3;       // hidden unit 0..63
  const int ko = tid & 7;       // K-octant (lane bits 0..2)
  const int k0 = ko << 3;
  const int bbase = blockIdx.x * NB;
  const bool kb0 = (ko & 1) != 0;
  const bool kb1 = (ko & 2) != 0;
  const bool wr = (ko == 0);

  // register-resident weights: 4 gate-rows x 8-wide K slice per matrix
  float whh0[4][8], wih1[4][8], whh1[4][8], wih2[4][8], whh2[4][8];
#pragma unroll
  for (int g = 0; g < 4; ++g) {
    const int r = (g << 6) + j;   // PyTorch gate-order rows: i,f,g,o
    const int ro = (r << 6) + k0;
    *(float4*)&whh0[g][0] = *(const float4*)&Whh0[ro];
    *(float4*)&whh0[g][4] = *(const float4*)&Whh0[ro + 4];
    *(float4*)&wih1[g][0] = *(const float4*)&Wih1[ro];
    *(float4*)&wih1[g][4] = *(const float4*)&Wih1[ro + 4];
    *(float4*)&whh1[g][0] = *(const float4*)&Whh1[ro];
    *(float4*)&whh1[g][4] = *(const float4*)&Whh1[ro + 4];
    *(float4*)&wih2[g][0] = *(const float4*)&Wih2[ro];
    *(float4*)&wih2[g][4] = *(const float4*)&Wih2[ro + 4];
    *(float4*)&whh2[g][0] = *(const float4*)&Whh2[ro];
    *(float4*)&whh2[g][4] = *(const float4*)&Whh2[ro + 4];
  }

  // per-lane gate-specific constants (gate = ko&3)
  const int gl = ko & 3;
  const int rl = (gl << 6) + j;
  const float b0l = bih0[rl] + bhh0[rl];
  const float b1l = bih1[rl] + bhh1[rl];
  const float b2l = bih2[rl] + bhh2[rl];
  float wi0l[4];
  {
    const float4 w0 = *(const float4*)&Wih0[rl * 4];
    wi0l[0] = w0.x; wi0l[1] = w0.y; wi0l[2] = w0.z; wi0l[3] = w0.w;
  }
  const bool isg = (gl == 2);
  const float kact = isg ? 2.8853900817779268f : -1.4426950408889634f;
  const float aact = isg ? -2.0f : 1.0f;
  const float bact = isg ? 1.0f : 0.0f;

  float c0[NB], c1[NB], c2[NB];
#pragma unroll
  for (int b = 0; b < NB; ++b) { c0[b] = 0.f; c1[b] = 0.f; c2[b] = 0.f; }

  {  // zero both parities of h
    float* p = &hb[0][0][0][0];
    for (int i = tid; i < 2 * 3 * NB * 64; i += NT) p[i] = 0.f;
  }

  // x prefetch (full 4-vector per batch elem, double-buffered)
  float xc[NB][4], xn[NB][4];
#pragma unroll
  for (int b = 0; b < NB; ++b) {
    const float4 v = *(const float4*)&x[(size_t)(bbase + b) * SS * 4];
    xc[b][0] = v.x; xc[b][1] = v.y; xc[b][2] = v.z; xc[b][3] = v.w;
  }
  __syncthreads();

#pragma unroll 1
  for (int t = 0; t < SS; t += 2) {
#pragma unroll
    for (int b = 0; b < NB; ++b) {
      const float4 v = *(const float4*)&x[((size_t)(bbase + b) * SS + (t + 1)) * 4];
      xn[b][0] = v.x; xn[b][1] = v.y; xn[b][2] = v.z; xn[b][3] = v.w;
    }
    lstm_step<0, 1>(hb, whh0, wih1, whh1, wih2, whh2, wi0l, b0l, b1l, b2l,
                    kact, aact, bact, c0, c1, c2, xc, j, ko, k0, kb0, kb1, wr);
    const int tp = (t + 2 < SS) ? (t + 2) : (SS - 1);
#pragma unroll
    for (int b = 0; b < NB; ++b) {
      const float4 v = *(const float4*)&x[((size_t)(bbase + b) * SS + tp) * 4];
      xc[b][0] = v.x; xc[b][1] = v.y; xc[b][2] = v.z; xc[b][3] = v.w;
    }
    lstm_step<1, 0>(hb, whh0, wih1, whh1, wih2, whh2, wi0l, b0l, b1l, b2l,
                    kact, aact, bact, c0, c1, c2, xn, j, ko, k0, kb0, kb1, wr);
  }
  __syncthreads();  // publish final h2 (parity 0 after t=2047)

  // fc: out[b][o] = fc_b[o] + sum_j fc_w[o][j] * h2_last[b][j]
  if (tid < NB * 2) {
    const int b = tid >> 1, o = tid & 1;
    float s = fcb[o];
#pragma unroll
    for (int jj = 0; jj < 64; ++jj)
      s = fmaf(fcw[o * 64 + jj], hb[0][2][b][jj], s);
    out[(bbase + b) * 2 + o] = s;
  }
}

extern "C" void kernel_launch(void* const* d_in, const int* in_sizes, int n_in,
                              void* d_out, int out_size, void* d_ws, size_t ws_size,
                              hipStream_t stream) {
  const float* x    = (const float*)d_in[0];
  const float* Wih0 = (const float*)d_in[1];
  const float* Whh0 = (const float*)d_in[2];
  const float* bih0 = (const float*)d_in[3];
  const float* bhh0 = (const float*)d_in[4];
  const float* Wih1 = (const float*)d_in[5];
  const float* Whh1 = (const float*)d_in[6];
  const float* bih1 = (const float*)d_in[7];
  const float* bhh1 = (const float*)d_in[8];
  const float* Wih2 = (const float*)d_in[9];
  const float* Whh2 = (const float*)d_in[10];
  const float* bih2 = (const float*)d_in[11];
  const float* bhh2 = (const float*)d_in[12];
  const float* fcw  = (const float*)d_in[13];
  const float* fcb  = (const float*)d_in[14];
  float* out = (float*)d_out;

  lstm3_kernel<<<dim3(BATCH / NB), dim3(NT), 0, stream>>>(
      x, Wih0, Whh0, bih0, bhh0, Wih1, Whh1, bih1, bhh1,
      Wih2, Whh2, bih2, bhh2, fcw, fcb, out);
}